// Round 8
// baseline (432.412 us; speedup 1.0000x reference)
//
#include <hip/hip_runtime.h>
#include <math.h>
#include <stdint.h>

#define NPTS   524288
#define TSZ    524288u
#define HMASK  (TSZ - 1u)
#define PRIME1 2654435761u
#define PRIME2 805459861u
#define NLVL   24

typedef float    v4f __attribute__((ext_vector_type(4)));
typedef _Float16 v4h __attribute__((ext_vector_type(4)));

#define MFMA16(A,B,C) __builtin_amdgcn_mfma_f32_16x16x16f16((A),(B),(C),0,0,0)

struct ResParams { float r[NLVL]; };

__device__ __forceinline__ uint32_t pack_f16x2(float a, float b) {
    union { _Float16 h[2]; uint32_t u; } c;
    c.h[0] = (_Float16)a; c.h[1] = (_Float16)b;
    return c.u;
}

__device__ __forceinline__ float softplus_f(float x) {
    return fmaxf(x, 0.f) + log1pf(expf(-fabsf(x)));
}

// ================= PASS 1: XCD-partitioned level-blocked hash gather ==========
// blockIdx→XCD is round-robin (bid&7). XCD x owns levels 3x..3x+2, so each
// XCD's 4MB L2 holds exactly one 4MB level slice at a time (no thrash).
// Plain float2 per-corner loads (R7 showed float4 x-pair merge regresses).
__global__ __launch_bounds__(256)
void hash_gather_pass(const float* __restrict__ points,
                      const float* __restrict__ table,
                      uint32_t* __restrict__ enc, ResParams rp)
{
    const int bid   = blockIdx.x;
    const int xcd   = bid & 7;
    const int j     = bid >> 3;            // 0..1535
    const int lvl   = xcd * 3 + (j >> 9);  // 3 levels per XCD, 512 chunks each
    const int chunk = j & 511;
    const float res = rp.r[lvl];
    const float* __restrict__ tl = table + (size_t)lvl * (size_t)(TSZ * 2u);
    uint32_t* __restrict__ el = enc + (size_t)lvl * (size_t)NPTS;
    const int pbase = chunk * 1024 + threadIdx.x;

    #pragma unroll
    for (int k = 0; k < 4; ++k) {
        const int p = pbase + k * 256;
        const float x0 = points[p * 3 + 0] * 0.5f + 0.5f;
        const float y0 = points[p * 3 + 1] * 0.5f + 0.5f;
        const float z0 = points[p * 3 + 2] * 0.5f + 0.5f;
        const float sx = x0 * res, sy = y0 * res, sz = z0 * res;
        const float fx = floorf(sx), fy = floorf(sy), fz = floorf(sz);
        const float tx = sx - fx,  ty = sy - fy,  tz = sz - fz;
        const uint32_t cx = (uint32_t)fx, cy = (uint32_t)fy, cz = (uint32_t)fz;
        const uint32_t hy0 = cy * PRIME1, hy1 = (cy + 1u) * PRIME1;
        const uint32_t hz0 = cz * PRIME2, hz1 = (cz + 1u) * PRIME2;
        const float wx[2] = {1.f - tx, tx};
        const float wy[2] = {1.f - ty, ty};
        const float wz[2] = {1.f - tz, tz};

        float a0 = 0.f, a1 = 0.f;
        #pragma unroll
        for (int corner = 0; corner < 8; ++corner) {
            const uint32_t dx = (uint32_t)(corner & 1);
            const uint32_t dy = (uint32_t)((corner >> 1) & 1);
            const uint32_t dz = (uint32_t)((corner >> 2) & 1);
            const uint32_t idx = ((cx + dx) ^ (dy ? hy1 : hy0) ^ (dz ? hz1 : hz0)) & HMASK;
            const float2 f2 = *reinterpret_cast<const float2*>(tl + (size_t)idx * 2u);
            const float w = wx[dx] * wy[dy] * wz[dz];
            a0 = fmaf(w, f2.x, a0);
            a1 = fmaf(w, f2.y, a1);
        }
        el[p] = pack_f16x2(a0 * 1024.f, a1 * 1024.f);
    }
}

// ================= PASS 2: MFMA MLP, swapped orientation D[out][pt] =================
// LDS byte offsets
#define SW0T   0        // f16 [32 out][52]   (K=48 pad, /1024 scaled)
#define SW1T   3328     // f16 [32][36]
#define SW2T   5632     // f16 [32][36]
#define SW3T   7936     // f16 [48 out][36]   (outs 33..47 zero)
#define SET    11392    // f16 [2][32 he][52] (E^T with +1 shift, o=0 & o>32 zero)
#define SB0    18048    // f32 [32]
#define SB1    18176
#define SB2    18304
#define SB3    18432    // f32 [48] (pad zero)
#define SEB0   18624    // f32 [2][32]
#define SEW1   18880    // f32 [2][32]
#define SEB1   19136    // f32 [2] (+pad)
#define SGEOM  19152    // f32 [4 waves][16][36]
#define SMB    28368

__global__ __launch_bounds__(256)
void mlp_mfma(const uint32_t* __restrict__ enc,
              const float* __restrict__ W0, const float* __restrict__ b0,
              const float* __restrict__ W1, const float* __restrict__ b1,
              const float* __restrict__ W2, const float* __restrict__ b2,
              const float* __restrict__ W3, const float* __restrict__ b3,
              const float* __restrict__ eW0, const float* __restrict__ eb0,
              const float* __restrict__ eW1, const float* __restrict__ eb1,
              float* __restrict__ out)
{
    __shared__ __align__(16) unsigned char sm[SMB];
    _Float16* const w0t = (_Float16*)(sm + SW0T);
    _Float16* const w1t = (_Float16*)(sm + SW1T);
    _Float16* const w2t = (_Float16*)(sm + SW2T);
    _Float16* const w3t = (_Float16*)(sm + SW3T);
    _Float16* const et  = (_Float16*)(sm + SET);
    float* const b0s  = (float*)(sm + SB0);
    float* const b1s  = (float*)(sm + SB1);
    float* const b2s  = (float*)(sm + SB2);
    float* const b3s  = (float*)(sm + SB3);
    float* const eb0s = (float*)(sm + SEB0);
    float* const ew1s = (float*)(sm + SEW1);
    float* const eb1s = (float*)(sm + SEB1);

    const int tid = threadIdx.x;

    // ---- stage + transform weights (once per block) ----
    for (int i = tid; i < 1536; i += 256) { const int k = i >> 5, o = i & 31;
        w0t[o * 52 + k] = (_Float16)(W0[i] * (1.f / 1024.f)); }
    for (int i = tid; i < 1024; i += 256) { const int k = i >> 5, o = i & 31;
        w1t[o * 36 + k] = (_Float16)W1[i];
        w2t[o * 36 + k] = (_Float16)W2[i]; }
    for (int i = tid; i < 1536; i += 256) { const int o = i >> 5, k = i & 31;
        w3t[o * 36 + k] = (o < 33) ? (_Float16)W3[k * 33 + o] : (_Float16)0.f; }
    for (int i = tid; i < 3328; i += 256) {
        const int hd = i / 1664, rem = i - hd * 1664;
        const int hh = rem / 52, o = rem % 52;
        et[i] = (o >= 1 && o <= 32) ? (_Float16)eW0[hd * 1024 + (o - 1) * 32 + hh]
                                    : (_Float16)0.f;
    }
    for (int i = tid; i < 32; i += 256) { b0s[i] = b0[i]; b1s[i] = b1[i]; b2s[i] = b2[i]; }
    for (int i = tid; i < 48; i += 256) { b3s[i] = (i < 33) ? b3[i] : 0.f; }
    for (int i = tid; i < 64; i += 256) { eb0s[i] = eb0[i]; ew1s[i] = eW1[i]; }
    if (tid < 2) eb1s[tid] = eb1[tid];
    __syncthreads();

    const int wv = tid >> 6, l = tid & 63, g = l >> 4, lm = l & 15;
    const size_t ptbase = (size_t)blockIdx.x * 256 + (size_t)wv * 64;

    // ---- enc B-frags: bx[tile][kc], direct u32 pairs from ws ----
    v4h bx[4][3];
    #pragma unroll
    for (int tt = 0; tt < 4; ++tt) {
        const size_t pt = ptbase + tt * 16 + lm;
        #pragma unroll
        for (int kc = 0; kc < 3; ++kc) {
            const int lv = 8 * kc + 2 * g;
            union { uint32_t u[2]; v4h h; } c;
            c.u[0] = enc[(size_t)lv * NPTS + pt];
            c.u[1] = enc[(size_t)(lv + 1) * NPTS + pt];
            bx[tt][kc] = c.h;
        }
    }

    // ---- L0: h = relu(W0^T · enc^T + b0) ----
    v4f acc[2][4];
    #pragma unroll
    for (int m = 0; m < 2; ++m) {
        const v4f bi = *(const v4f*)(b0s + 16 * m + 4 * g);
        const v4h a0f = *(const v4h*)(w0t + (16 * m + lm) * 52 + 4 * g);
        const v4h a1f = *(const v4h*)(w0t + (16 * m + lm) * 52 + 16 + 4 * g);
        const v4h a2f = *(const v4h*)(w0t + (16 * m + lm) * 52 + 32 + 4 * g);
        #pragma unroll
        for (int tt = 0; tt < 4; ++tt) {
            v4f a = bi;
            a = MFMA16(a0f, bx[tt][0], a);
            a = MFMA16(a1f, bx[tt][1], a);
            a = MFMA16(a2f, bx[tt][2], a);
            acc[m][tt] = a;
        }
    }
    v4h bh[4][2];
    #pragma unroll
    for (int tt = 0; tt < 4; ++tt)
        #pragma unroll
        for (int m = 0; m < 2; ++m) {
            v4h h;
            #pragma unroll
            for (int r = 0; r < 4; ++r) h[r] = (_Float16)fmaxf(acc[m][tt][r], 0.f);
            bh[tt][m] = h;
        }

    // ---- L1 ----
    #pragma unroll
    for (int m = 0; m < 2; ++m) {
        const v4f bi = *(const v4f*)(b1s + 16 * m + 4 * g);
        const v4h a0f = *(const v4h*)(w1t + (16 * m + lm) * 36 + 4 * g);
        const v4h a1f = *(const v4h*)(w1t + (16 * m + lm) * 36 + 16 + 4 * g);
        #pragma unroll
        for (int tt = 0; tt < 4; ++tt) {
            v4f a = bi;
            a = MFMA16(a0f, bh[tt][0], a);
            a = MFMA16(a1f, bh[tt][1], a);
            acc[m][tt] = a;
        }
    }
    #pragma unroll
    for (int tt = 0; tt < 4; ++tt)
        #pragma unroll
        for (int m = 0; m < 2; ++m) {
            v4h h;
            #pragma unroll
            for (int r = 0; r < 4; ++r) h[r] = (_Float16)fmaxf(acc[m][tt][r], 0.f);
            bh[tt][m] = h;
        }

    // ---- L2 ----
    #pragma unroll
    for (int m = 0; m < 2; ++m) {
        const v4f bi = *(const v4f*)(b2s + 16 * m + 4 * g);
        const v4h a0f = *(const v4h*)(w2t + (16 * m + lm) * 36 + 4 * g);
        const v4h a1f = *(const v4h*)(w2t + (16 * m + lm) * 36 + 16 + 4 * g);
        #pragma unroll
        for (int tt = 0; tt < 4; ++tt) {
            v4f a = bi;
            a = MFMA16(a0f, bh[tt][0], a);
            a = MFMA16(a1f, bh[tt][1], a);
            acc[m][tt] = a;
        }
    }
    #pragma unroll
    for (int tt = 0; tt < 4; ++tt)
        #pragma unroll
        for (int m = 0; m < 2; ++m) {
            v4h h;
            #pragma unroll
            for (int r = 0; r < 4; ++r) h[r] = (_Float16)fmaxf(acc[m][tt][r], 0.f);
            bh[tt][m] = h;
        }

    // ---- L3: pred = W3^T·h + b3 (outs 0..32 real, 33..47 zero) ----
    v4f acc3[3][4];
    #pragma unroll
    for (int m = 0; m < 3; ++m) {
        const v4f bi = *(const v4f*)(b3s + 16 * m + 4 * g);
        const v4h a0f = *(const v4h*)(w3t + (16 * m + lm) * 36 + 4 * g);
        const v4h a1f = *(const v4h*)(w3t + (16 * m + lm) * 36 + 16 + 4 * g);
        #pragma unroll
        for (int tt = 0; tt < 4; ++tt) {
            v4f a = bi;
            a = MFMA16(a0f, bh[tt][0], a);
            a = MFMA16(a1f, bh[tt][1], a);
            acc3[m][tt] = a;
        }
    }
    v4h pf[4][3];
    #pragma unroll
    for (int tt = 0; tt < 4; ++tt)
        #pragma unroll
        for (int m = 0; m < 3; ++m) {
            v4h h;
            #pragma unroll
            for (int r = 0; r < 4; ++r) h[r] = (_Float16)acc3[m][tt][r];
            pf[tt][m] = h;
        }

    // ---- eps heads: he = relu(E^T·pred^T + eb0); eps = he·eW1 + eb1 ----
    float ep[2][4];
    #pragma unroll
    for (int k = 0; k < 2; ++k) {
        const v4f bi0 = *(const v4f*)(eb0s + k * 32 + 4 * g);
        const v4f bi1 = *(const v4f*)(eb0s + k * 32 + 16 + 4 * g);
        const v4f w10 = *(const v4f*)(ew1s + k * 32 + 4 * g);
        const v4f w11 = *(const v4f*)(ew1s + k * 32 + 16 + 4 * g);
        const _Float16* eb = et + (size_t)k * 1664;
        const v4h e00 = *(const v4h*)(eb + lm * 52 + 4 * g);
        const v4h e01 = *(const v4h*)(eb + lm * 52 + 16 + 4 * g);
        const v4h e02 = *(const v4h*)(eb + lm * 52 + 32 + 4 * g);
        const v4h e10 = *(const v4h*)(eb + (16 + lm) * 52 + 4 * g);
        const v4h e11 = *(const v4h*)(eb + (16 + lm) * 52 + 16 + 4 * g);
        const v4h e12 = *(const v4h*)(eb + (16 + lm) * 52 + 32 + 4 * g);
        #pragma unroll
        for (int tt = 0; tt < 4; ++tt) {
            v4f h0 = bi0, h1 = bi1;
            h0 = MFMA16(e00, pf[tt][0], h0);
            h0 = MFMA16(e01, pf[tt][1], h0);
            h0 = MFMA16(e02, pf[tt][2], h0);
            h1 = MFMA16(e10, pf[tt][0], h1);
            h1 = MFMA16(e11, pf[tt][1], h1);
            h1 = MFMA16(e12, pf[tt][2], h1);
            float p = fmaxf(h0[0], 0.f) * w10[0] + fmaxf(h0[1], 0.f) * w10[1]
                    + fmaxf(h0[2], 0.f) * w10[2] + fmaxf(h0[3], 0.f) * w10[3]
                    + fmaxf(h1[0], 0.f) * w11[0] + fmaxf(h1[1], 0.f) * w11[1]
                    + fmaxf(h1[2], 0.f) * w11[2] + fmaxf(h1[3], 0.f) * w11[3];
            p += __shfl_xor(p, 16);
            p += __shfl_xor(p, 32);
            ep[k][tt] = p + eb1s[k];
        }
    }

    // ---- epilogue: geom via LDS bounce (coalesced), sdfs/offsets by lanes<16 ----
    float* const gw = (float*)(sm + SGEOM) + wv * (16 * 36);
    #pragma unroll
    for (int tt = 0; tt < 4; ++tt) {
        #pragma unroll
        for (int m = 0; m < 3; ++m)
            #pragma unroll
            for (int r = 0; r < 4; ++r) {
                const int o = 16 * m + 4 * g + r;
                if (o >= 1 && o <= 32) gw[lm * 36 + o - 1] = acc3[m][tt][r];
            }
        __syncthreads();
        {
            const int pl = l >> 2, q = l & 3;
            const v4f g0 = *(const v4f*)(gw + pl * 36 + q * 8);
            const v4f g1 = *(const v4f*)(gw + pl * 36 + q * 8 + 4);
            float* og = out + (size_t)NPTS * 6 + (ptbase + tt * 16 + pl) * 32 + q * 8;
            *reinterpret_cast<v4f*>(og)     = g0;
            *reinterpret_cast<v4f*>(og + 4) = g1;
        }
        if (l < 16) {
            const size_t pid = ptbase + tt * 16 + l;
            const float sdf   = acc3[0][tt][0];
            const float inner = softplus_f(ep[1][tt]);
            const float outer = -softplus_f(ep[0][tt]);
            out[pid * 3 + 0] = sdf + inner + 1e-4f;
            out[pid * 3 + 1] = sdf;
            out[pid * 3 + 2] = sdf + outer - 1e-4f;
            float* oo = out + (size_t)NPTS * 3 + pid * 3;
            oo[0] = inner; oo[1] = 0.f; oo[2] = outer;
        }
        __syncthreads();
    }
}

extern "C" void kernel_launch(void* const* d_in, const int* in_sizes, int n_in,
                              void* d_out, int out_size, void* d_ws, size_t ws_size,
                              hipStream_t stream) {
    const float* points = (const float*)d_in[0];
    const float* table  = (const float*)d_in[1];
    const float* W0  = (const float*)d_in[2];
    const float* b0  = (const float*)d_in[3];
    const float* W1  = (const float*)d_in[4];
    const float* b1  = (const float*)d_in[5];
    const float* W2  = (const float*)d_in[6];
    const float* b2  = (const float*)d_in[7];
    const float* W3  = (const float*)d_in[8];
    const float* b3  = (const float*)d_in[9];
    const float* eW0 = (const float*)d_in[10];
    const float* eb0 = (const float*)d_in[11];
    const float* eW1 = (const float*)d_in[12];
    const float* eb1 = (const float*)d_in[13];
    float* out = (float*)d_out;

    ResParams rp;
    for (int l = 0; l < NLVL; ++l)
        rp.r[l] = (float)floor(16.0 * exp((double)l * log(2048.0 / 16.0) / 23.0));
    (void)in_sizes; (void)n_in; (void)out_size; (void)ws_size;

    uint32_t* enc = (uint32_t*)d_ws;   // 50.3 MB
    hash_gather_pass<<<dim3(NLVL * 512), dim3(256), 0, stream>>>(points, table, enc, rp);
    mlp_mfma<<<dim3(NPTS / 256), dim3(256), 0, stream>>>(
        enc, W0, b0, W1, b1, W2, b2, W3, b3, eW0, eb0, eW1, eb1, out);
}

// Round 9
// 397.427 us; speedup vs baseline: 1.0880x; 1.0880x over previous
//
#include <hip/hip_runtime.h>
#include <math.h>
#include <stdint.h>

#define NPTS   524288
#define TSZ    524288u
#define HMASK  (TSZ - 1u)
#define PRIME1 2654435761u
#define PRIME2 805459861u
#define NLVL   24

typedef float    v4f __attribute__((ext_vector_type(4)));
typedef _Float16 v4h __attribute__((ext_vector_type(4)));

#define MFMA16(A,B,C) __builtin_amdgcn_mfma_f32_16x16x16f16((A),(B),(C),0,0,0)

struct ResParams { float r[NLVL]; };

__device__ __forceinline__ uint32_t pack_f16x2(float a, float b) {
    union { _Float16 h[2]; uint32_t u; } c;
    c.h[0] = (_Float16)a; c.h[1] = (_Float16)b;
    return c.u;
}

__device__ __forceinline__ float softplus_f(float x) {
    return fmaxf(x, 0.f) + log1pf(expf(-fabsf(x)));
}

// ================= PASS 1: XCD-striped level-blocked hash gather ==========
// blockIdx→XCD is round-robin (bid&7). XCD x owns levels {x, x+8, x+16} in
// three sequential phases — one cheap (L1-resident), one mid, one expensive
// (random 4MB) level per XCD: balanced runtime AND per-phase L2 fit.
__global__ __launch_bounds__(256)
void hash_gather_pass(const float* __restrict__ points,
                      const float* __restrict__ table,
                      uint32_t* __restrict__ enc, ResParams rp)
{
    const int bid   = blockIdx.x;
    const int xcd   = bid & 7;
    const int j     = bid >> 3;            // 0..1535
    const int lvl   = ((j >> 9) << 3) + xcd;  // phase*8 + xcd
    const int chunk = j & 511;
    const float res = rp.r[lvl];
    const float* __restrict__ tl = table + (size_t)lvl * (size_t)(TSZ * 2u);
    uint32_t* __restrict__ el = enc + (size_t)lvl * (size_t)NPTS;
    const int pbase = chunk * 1024 + threadIdx.x;

    #pragma unroll
    for (int k = 0; k < 4; ++k) {
        const int p = pbase + k * 256;
        const float x0 = points[p * 3 + 0] * 0.5f + 0.5f;
        const float y0 = points[p * 3 + 1] * 0.5f + 0.5f;
        const float z0 = points[p * 3 + 2] * 0.5f + 0.5f;
        const float sx = x0 * res, sy = y0 * res, sz = z0 * res;
        const float fx = floorf(sx), fy = floorf(sy), fz = floorf(sz);
        const float tx = sx - fx,  ty = sy - fy,  tz = sz - fz;
        const uint32_t cx = (uint32_t)fx, cy = (uint32_t)fy, cz = (uint32_t)fz;
        const uint32_t hy0 = cy * PRIME1, hy1 = (cy + 1u) * PRIME1;
        const uint32_t hz0 = cz * PRIME2, hz1 = (cz + 1u) * PRIME2;
        const float wx[2] = {1.f - tx, tx};
        const float wy[2] = {1.f - ty, ty};
        const float wz[2] = {1.f - tz, tz};

        float a0 = 0.f, a1 = 0.f;
        #pragma unroll
        for (int corner = 0; corner < 8; ++corner) {
            const uint32_t dx = (uint32_t)(corner & 1);
            const uint32_t dy = (uint32_t)((corner >> 1) & 1);
            const uint32_t dz = (uint32_t)((corner >> 2) & 1);
            const uint32_t idx = ((cx + dx) ^ (dy ? hy1 : hy0) ^ (dz ? hz1 : hz0)) & HMASK;
            const float2 f2 = *reinterpret_cast<const float2*>(tl + (size_t)idx * 2u);
            const float w = wx[dx] * wy[dy] * wz[dz];
            a0 = fmaf(w, f2.x, a0);
            a1 = fmaf(w, f2.y, a1);
        }
        el[p] = pack_f16x2(a0 * 1024.f, a1 * 1024.f);
    }
}

// ================= PASS 2: MFMA MLP, swapped orientation D[out][pt] =================
// LDS byte offsets
#define SW0T   0        // f16 [32 out][52]   (K=48 pad, /1024 scaled)
#define SW1T   3328     // f16 [32][36]
#define SW2T   5632     // f16 [32][36]
#define SW3T   7936     // f16 [48 out][36]   (outs 33..47 zero)
#define SET    11392    // f16 [2][32 he][52] (E^T with +1 shift, o=0 & o>32 zero)
#define SB0    18048    // f32 [32]
#define SB1    18176
#define SB2    18304
#define SB3    18432    // f32 [48] (pad zero)
#define SEB0   18624    // f32 [2][32]
#define SEW1   18880    // f32 [2][32]
#define SEB1   19136    // f32 [2] (+pad)
#define SGEOM  19152    // f32 [4 waves][16][36]
#define SMB    28368

__global__ __launch_bounds__(256)
void mlp_mfma(const uint32_t* __restrict__ enc,
              const float* __restrict__ W0, const float* __restrict__ b0,
              const float* __restrict__ W1, const float* __restrict__ b1,
              const float* __restrict__ W2, const float* __restrict__ b2,
              const float* __restrict__ W3, const float* __restrict__ b3,
              const float* __restrict__ eW0, const float* __restrict__ eb0,
              const float* __restrict__ eW1, const float* __restrict__ eb1,
              float* __restrict__ out)
{
    __shared__ __align__(16) unsigned char sm[SMB];
    _Float16* const w0t = (_Float16*)(sm + SW0T);
    _Float16* const w1t = (_Float16*)(sm + SW1T);
    _Float16* const w2t = (_Float16*)(sm + SW2T);
    _Float16* const w3t = (_Float16*)(sm + SW3T);
    _Float16* const et  = (_Float16*)(sm + SET);
    float* const b0s  = (float*)(sm + SB0);
    float* const b1s  = (float*)(sm + SB1);
    float* const b2s  = (float*)(sm + SB2);
    float* const b3s  = (float*)(sm + SB3);
    float* const eb0s = (float*)(sm + SEB0);
    float* const ew1s = (float*)(sm + SEW1);
    float* const eb1s = (float*)(sm + SEB1);

    const int tid = threadIdx.x;

    // ---- stage + transform weights (once per block) ----
    for (int i = tid; i < 1536; i += 256) { const int k = i >> 5, o = i & 31;
        w0t[o * 52 + k] = (_Float16)(W0[i] * (1.f / 1024.f)); }
    for (int i = tid; i < 1024; i += 256) { const int k = i >> 5, o = i & 31;
        w1t[o * 36 + k] = (_Float16)W1[i];
        w2t[o * 36 + k] = (_Float16)W2[i]; }
    for (int i = tid; i < 1536; i += 256) { const int o = i >> 5, k = i & 31;
        w3t[o * 36 + k] = (o < 33) ? (_Float16)W3[k * 33 + o] : (_Float16)0.f; }
    for (int i = tid; i < 3328; i += 256) {
        const int hd = i / 1664, rem = i - hd * 1664;
        const int hh = rem / 52, o = rem % 52;
        et[i] = (o >= 1 && o <= 32) ? (_Float16)eW0[hd * 1024 + (o - 1) * 32 + hh]
                                    : (_Float16)0.f;
    }
    for (int i = tid; i < 32; i += 256) { b0s[i] = b0[i]; b1s[i] = b1[i]; b2s[i] = b2[i]; }
    for (int i = tid; i < 48; i += 256) { b3s[i] = (i < 33) ? b3[i] : 0.f; }
    for (int i = tid; i < 64; i += 256) { eb0s[i] = eb0[i]; ew1s[i] = eW1[i]; }
    if (tid < 2) eb1s[tid] = eb1[tid];
    __syncthreads();

    const int wv = tid >> 6, l = tid & 63, g = l >> 4, lm = l & 15;
    const size_t ptbase = (size_t)blockIdx.x * 256 + (size_t)wv * 64;

    // ---- enc B-frags: bx[tile][kc], direct u32 pairs from ws ----
    v4h bx[4][3];
    #pragma unroll
    for (int tt = 0; tt < 4; ++tt) {
        const size_t pt = ptbase + tt * 16 + lm;
        #pragma unroll
        for (int kc = 0; kc < 3; ++kc) {
            const int lv = 8 * kc + 2 * g;
            union { uint32_t u[2]; v4h h; } c;
            c.u[0] = enc[(size_t)lv * NPTS + pt];
            c.u[1] = enc[(size_t)(lv + 1) * NPTS + pt];
            bx[tt][kc] = c.h;
        }
    }

    // ---- L0: h = relu(W0^T · enc^T + b0) ----
    v4f acc[2][4];
    #pragma unroll
    for (int m = 0; m < 2; ++m) {
        const v4f bi = *(const v4f*)(b0s + 16 * m + 4 * g);
        const v4h a0f = *(const v4h*)(w0t + (16 * m + lm) * 52 + 4 * g);
        const v4h a1f = *(const v4h*)(w0t + (16 * m + lm) * 52 + 16 + 4 * g);
        const v4h a2f = *(const v4h*)(w0t + (16 * m + lm) * 52 + 32 + 4 * g);
        #pragma unroll
        for (int tt = 0; tt < 4; ++tt) {
            v4f a = bi;
            a = MFMA16(a0f, bx[tt][0], a);
            a = MFMA16(a1f, bx[tt][1], a);
            a = MFMA16(a2f, bx[tt][2], a);
            acc[m][tt] = a;
        }
    }
    v4h bh[4][2];
    #pragma unroll
    for (int tt = 0; tt < 4; ++tt)
        #pragma unroll
        for (int m = 0; m < 2; ++m) {
            v4h h;
            #pragma unroll
            for (int r = 0; r < 4; ++r) h[r] = (_Float16)fmaxf(acc[m][tt][r], 0.f);
            bh[tt][m] = h;
        }

    // ---- L1 ----
    #pragma unroll
    for (int m = 0; m < 2; ++m) {
        const v4f bi = *(const v4f*)(b1s + 16 * m + 4 * g);
        const v4h a0f = *(const v4h*)(w1t + (16 * m + lm) * 36 + 4 * g);
        const v4h a1f = *(const v4h*)(w1t + (16 * m + lm) * 36 + 16 + 4 * g);
        #pragma unroll
        for (int tt = 0; tt < 4; ++tt) {
            v4f a = bi;
            a = MFMA16(a0f, bh[tt][0], a);
            a = MFMA16(a1f, bh[tt][1], a);
            acc[m][tt] = a;
        }
    }
    #pragma unroll
    for (int tt = 0; tt < 4; ++tt)
        #pragma unroll
        for (int m = 0; m < 2; ++m) {
            v4h h;
            #pragma unroll
            for (int r = 0; r < 4; ++r) h[r] = (_Float16)fmaxf(acc[m][tt][r], 0.f);
            bh[tt][m] = h;
        }

    // ---- L2 ----
    #pragma unroll
    for (int m = 0; m < 2; ++m) {
        const v4f bi = *(const v4f*)(b2s + 16 * m + 4 * g);
        const v4h a0f = *(const v4h*)(w2t + (16 * m + lm) * 36 + 4 * g);
        const v4h a1f = *(const v4h*)(w2t + (16 * m + lm) * 36 + 16 + 4 * g);
        #pragma unroll
        for (int tt = 0; tt < 4; ++tt) {
            v4f a = bi;
            a = MFMA16(a0f, bh[tt][0], a);
            a = MFMA16(a1f, bh[tt][1], a);
            acc[m][tt] = a;
        }
    }
    #pragma unroll
    for (int tt = 0; tt < 4; ++tt)
        #pragma unroll
        for (int m = 0; m < 2; ++m) {
            v4h h;
            #pragma unroll
            for (int r = 0; r < 4; ++r) h[r] = (_Float16)fmaxf(acc[m][tt][r], 0.f);
            bh[tt][m] = h;
        }

    // ---- L3: pred = W3^T·h + b3 (outs 0..32 real, 33..47 zero) ----
    v4f acc3[3][4];
    #pragma unroll
    for (int m = 0; m < 3; ++m) {
        const v4f bi = *(const v4f*)(b3s + 16 * m + 4 * g);
        const v4h a0f = *(const v4h*)(w3t + (16 * m + lm) * 36 + 4 * g);
        const v4h a1f = *(const v4h*)(w3t + (16 * m + lm) * 36 + 16 + 4 * g);
        #pragma unroll
        for (int tt = 0; tt < 4; ++tt) {
            v4f a = bi;
            a = MFMA16(a0f, bh[tt][0], a);
            a = MFMA16(a1f, bh[tt][1], a);
            acc3[m][tt] = a;
        }
    }
    v4h pf[4][3];
    #pragma unroll
    for (int tt = 0; tt < 4; ++tt)
        #pragma unroll
        for (int m = 0; m < 3; ++m) {
            v4h h;
            #pragma unroll
            for (int r = 0; r < 4; ++r) h[r] = (_Float16)acc3[m][tt][r];
            pf[tt][m] = h;
        }

    // ---- eps heads: he = relu(E^T·pred^T + eb0); eps = he·eW1 + eb1 ----
    float ep[2][4];
    #pragma unroll
    for (int k = 0; k < 2; ++k) {
        const v4f bi0 = *(const v4f*)(eb0s + k * 32 + 4 * g);
        const v4f bi1 = *(const v4f*)(eb0s + k * 32 + 16 + 4 * g);
        const v4f w10 = *(const v4f*)(ew1s + k * 32 + 4 * g);
        const v4f w11 = *(const v4f*)(ew1s + k * 32 + 16 + 4 * g);
        const _Float16* eb = et + (size_t)k * 1664;
        const v4h e00 = *(const v4h*)(eb + lm * 52 + 4 * g);
        const v4h e01 = *(const v4h*)(eb + lm * 52 + 16 + 4 * g);
        const v4h e02 = *(const v4h*)(eb + lm * 52 + 32 + 4 * g);
        const v4h e10 = *(const v4h*)(eb + (16 + lm) * 52 + 4 * g);
        const v4h e11 = *(const v4h*)(eb + (16 + lm) * 52 + 16 + 4 * g);
        const v4h e12 = *(const v4h*)(eb + (16 + lm) * 52 + 32 + 4 * g);
        #pragma unroll
        for (int tt = 0; tt < 4; ++tt) {
            v4f h0 = bi0, h1 = bi1;
            h0 = MFMA16(e00, pf[tt][0], h0);
            h0 = MFMA16(e01, pf[tt][1], h0);
            h0 = MFMA16(e02, pf[tt][2], h0);
            h1 = MFMA16(e10, pf[tt][0], h1);
            h1 = MFMA16(e11, pf[tt][1], h1);
            h1 = MFMA16(e12, pf[tt][2], h1);
            float p = fmaxf(h0[0], 0.f) * w10[0] + fmaxf(h0[1], 0.f) * w10[1]
                    + fmaxf(h0[2], 0.f) * w10[2] + fmaxf(h0[3], 0.f) * w10[3]
                    + fmaxf(h1[0], 0.f) * w11[0] + fmaxf(h1[1], 0.f) * w11[1]
                    + fmaxf(h1[2], 0.f) * w11[2] + fmaxf(h1[3], 0.f) * w11[3];
            p += __shfl_xor(p, 16);
            p += __shfl_xor(p, 32);
            ep[k][tt] = p + eb1s[k];
        }
    }

    // ---- epilogue: geom via LDS bounce (coalesced), sdfs/offsets by lanes<16 ----
    float* const gw = (float*)(sm + SGEOM) + wv * (16 * 36);
    #pragma unroll
    for (int tt = 0; tt < 4; ++tt) {
        #pragma unroll
        for (int m = 0; m < 3; ++m)
            #pragma unroll
            for (int r = 0; r < 4; ++r) {
                const int o = 16 * m + 4 * g + r;
                if (o >= 1 && o <= 32) gw[lm * 36 + o - 1] = acc3[m][tt][r];
            }
        __syncthreads();
        {
            const int pl = l >> 2, q = l & 3;
            const v4f g0 = *(const v4f*)(gw + pl * 36 + q * 8);
            const v4f g1 = *(const v4f*)(gw + pl * 36 + q * 8 + 4);
            float* og = out + (size_t)NPTS * 6 + (ptbase + tt * 16 + pl) * 32 + q * 8;
            *reinterpret_cast<v4f*>(og)     = g0;
            *reinterpret_cast<v4f*>(og + 4) = g1;
        }
        if (l < 16) {
            const size_t pid = ptbase + tt * 16 + l;
            const float sdf   = acc3[0][tt][0];
            const float inner = softplus_f(ep[1][tt]);
            const float outer = -softplus_f(ep[0][tt]);
            out[pid * 3 + 0] = sdf + inner + 1e-4f;
            out[pid * 3 + 1] = sdf;
            out[pid * 3 + 2] = sdf + outer - 1e-4f;
            float* oo = out + (size_t)NPTS * 3 + pid * 3;
            oo[0] = inner; oo[1] = 0.f; oo[2] = outer;
        }
        __syncthreads();
    }
}

extern "C" void kernel_launch(void* const* d_in, const int* in_sizes, int n_in,
                              void* d_out, int out_size, void* d_ws, size_t ws_size,
                              hipStream_t stream) {
    const float* points = (const float*)d_in[0];
    const float* table  = (const float*)d_in[1];
    const float* W0  = (const float*)d_in[2];
    const float* b0  = (const float*)d_in[3];
    const float* W1  = (const float*)d_in[4];
    const float* b1  = (const float*)d_in[5];
    const float* W2  = (const float*)d_in[6];
    const float* b2  = (const float*)d_in[7];
    const float* W3  = (const float*)d_in[8];
    const float* b3  = (const float*)d_in[9];
    const float* eW0 = (const float*)d_in[10];
    const float* eb0 = (const float*)d_in[11];
    const float* eW1 = (const float*)d_in[12];
    const float* eb1 = (const float*)d_in[13];
    float* out = (float*)d_out;

    ResParams rp;
    for (int l = 0; l < NLVL; ++l)
        rp.r[l] = (float)floor(16.0 * exp((double)l * log(2048.0 / 16.0) / 23.0));
    (void)in_sizes; (void)n_in; (void)out_size; (void)ws_size;

    uint32_t* enc = (uint32_t*)d_ws;   // 50.3 MB
    hash_gather_pass<<<dim3(NLVL * 512), dim3(256), 0, stream>>>(points, table, enc, rp);
    mlp_mfma<<<dim3(NPTS / 256), dim3(256), 0, stream>>>(
        enc, W0, b0, W1, b1, W2, b2, W3, b3, eW0, eb0, eW1, eb1, out);
}

// Round 10
// 315.965 us; speedup vs baseline: 1.3685x; 1.2578x over previous
//
#include <hip/hip_runtime.h>
#include <math.h>
#include <stdint.h>

#define NPTS   524288
#define TSZ    524288u
#define HMASK  (TSZ - 1u)
#define PRIME1 2654435761u
#define PRIME2 805459861u
#define NLVL   24

typedef float    v4f __attribute__((ext_vector_type(4)));
typedef _Float16 v4h __attribute__((ext_vector_type(4)));

#define MFMA16(A,B,C) __builtin_amdgcn_mfma_f32_16x16x16f16((A),(B),(C),0,0,0)

struct ResParams { float r[NLVL]; };

__device__ __forceinline__ uint32_t pack_f16x2(float a, float b) {
    union { _Float16 h[2]; uint32_t u; } c;
    c.h[0] = (_Float16)a; c.h[1] = (_Float16)b;
    return c.u;
}

__device__ __forceinline__ float softplus_f(float x) {
    return fmaxf(x, 0.f) + log1pf(expf(-fabsf(x)));
}

// ================= PASS 1: XCD-striped gather + parity x-pair merge ==========
// XCD x owns levels {x, x+8, x+16} (R9 striping, kept). NEW: when cx is even,
// the two x-corners live in the same 16B-aligned entry pair -> ONE float4 load
// (exact bytes). Odd cx keeps two float2 loads. ~25% fewer L2 requests.
__global__ __launch_bounds__(256)
void hash_gather_pass(const float* __restrict__ points,
                      const float* __restrict__ table,
                      uint32_t* __restrict__ enc, ResParams rp)
{
    const int bid   = blockIdx.x;
    const int xcd   = bid & 7;
    const int j     = bid >> 3;            // 0..1535
    const int lvl   = ((j >> 9) << 3) + xcd;  // phase*8 + xcd
    const int chunk = j & 511;
    const float res = rp.r[lvl];
    const float* __restrict__ tl = table + (size_t)lvl * (size_t)(TSZ * 2u);
    uint32_t* __restrict__ el = enc + (size_t)lvl * (size_t)NPTS;
    const int pbase = chunk * 1024 + threadIdx.x;

    #pragma unroll
    for (int k = 0; k < 4; ++k) {
        const int p = pbase + k * 256;
        const float x0 = points[p * 3 + 0] * 0.5f + 0.5f;
        const float y0 = points[p * 3 + 1] * 0.5f + 0.5f;
        const float z0 = points[p * 3 + 2] * 0.5f + 0.5f;
        const float sx = x0 * res, sy = y0 * res, sz = z0 * res;
        const float fx = floorf(sx), fy = floorf(sy), fz = floorf(sz);
        const float tx = sx - fx,  ty = sy - fy,  tz = sz - fz;
        const uint32_t cx = (uint32_t)fx, cy = (uint32_t)fy, cz = (uint32_t)fz;
        const uint32_t hy0 = cy * PRIME1, hy1 = (cy + 1u) * PRIME1;
        const uint32_t hz0 = cz * PRIME2, hz1 = (cz + 1u) * PRIME2;
        const float wy[2] = {1.f - ty, ty};
        const float wz[2] = {1.f - tz, tz};
        const float wx0 = 1.f - tx, wx1 = tx;
        const bool cx_even = (cx & 1u) == 0u;

        float a0 = 0.f, a1 = 0.f;
        #pragma unroll
        for (int yz = 0; yz < 4; ++yz) {
            const uint32_t dy = (uint32_t)(yz & 1);
            const uint32_t dz = (uint32_t)(yz >> 1);
            const uint32_t h  = (dy ? hy1 : hy0) ^ (dz ? hz1 : hz0);
            const uint32_t i0 = (cx ^ h) & HMASK;          // x = cx
            const uint32_t i1 = ((cx + 1u) ^ h) & HMASK;   // x = cx+1
            float e0x, e0y, e1x, e1y;
            if (cx_even) {
                // i1 == i0^1: both entries in one 16B-aligned pair -> 1 load
                const float4 f4 = *reinterpret_cast<const float4*>(tl + (size_t)(i0 & ~1u) * 2u);
                const bool lo = (i0 & 1u) == 0u;   // is e0 the low entry?
                e0x = lo ? f4.x : f4.z;  e0y = lo ? f4.y : f4.w;
                e1x = lo ? f4.z : f4.x;  e1y = lo ? f4.w : f4.y;
            } else {
                const float2 fa = *reinterpret_cast<const float2*>(tl + (size_t)i0 * 2u);
                const float2 fb = *reinterpret_cast<const float2*>(tl + (size_t)i1 * 2u);
                e0x = fa.x; e0y = fa.y; e1x = fb.x; e1y = fb.y;
            }
            const float wyz = wy[dy] * wz[dz];
            const float w0 = wyz * wx0, w1 = wyz * wx1;
            a0 = fmaf(w0, e0x, fmaf(w1, e1x, a0));
            a1 = fmaf(w0, e0y, fmaf(w1, e1y, a1));
        }
        el[p] = pack_f16x2(a0 * 1024.f, a1 * 1024.f);
    }
}

// ================= PASS 2: MFMA MLP, swapped orientation D[out][pt] =================
// LDS byte offsets
#define SW0T   0        // f16 [32 out][52]   (K=48 pad, /1024 scaled)
#define SW1T   3328     // f16 [32][36]
#define SW2T   5632     // f16 [32][36]
#define SW3T   7936     // f16 [48 out][36]   (outs 33..47 zero)
#define SET    11392    // f16 [2][32 he][52] (E^T with +1 shift, o=0 & o>32 zero)
#define SB0    18048    // f32 [32]
#define SB1    18176
#define SB2    18304
#define SB3    18432    // f32 [48] (pad zero)
#define SEB0   18624    // f32 [2][32]
#define SEW1   18880    // f32 [2][32]
#define SEB1   19136    // f32 [2] (+pad)
#define SGEOM  19152    // f32 [4 waves][16][36]
#define SMB    28368

__global__ __launch_bounds__(256)
void mlp_mfma(const uint32_t* __restrict__ enc,
              const float* __restrict__ W0, const float* __restrict__ b0,
              const float* __restrict__ W1, const float* __restrict__ b1,
              const float* __restrict__ W2, const float* __restrict__ b2,
              const float* __restrict__ W3, const float* __restrict__ b3,
              const float* __restrict__ eW0, const float* __restrict__ eb0,
              const float* __restrict__ eW1, const float* __restrict__ eb1,
              float* __restrict__ out)
{
    __shared__ __align__(16) unsigned char sm[SMB];
    _Float16* const w0t = (_Float16*)(sm + SW0T);
    _Float16* const w1t = (_Float16*)(sm + SW1T);
    _Float16* const w2t = (_Float16*)(sm + SW2T);
    _Float16* const w3t = (_Float16*)(sm + SW3T);
    _Float16* const et  = (_Float16*)(sm + SET);
    float* const b0s  = (float*)(sm + SB0);
    float* const b1s  = (float*)(sm + SB1);
    float* const b2s  = (float*)(sm + SB2);
    float* const b3s  = (float*)(sm + SB3);
    float* const eb0s = (float*)(sm + SEB0);
    float* const ew1s = (float*)(sm + SEW1);
    float* const eb1s = (float*)(sm + SEB1);

    const int tid = threadIdx.x;

    // ---- stage + transform weights (once per block) ----
    for (int i = tid; i < 1536; i += 256) { const int k = i >> 5, o = i & 31;
        w0t[o * 52 + k] = (_Float16)(W0[i] * (1.f / 1024.f)); }
    for (int i = tid; i < 1024; i += 256) { const int k = i >> 5, o = i & 31;
        w1t[o * 36 + k] = (_Float16)W1[i];
        w2t[o * 36 + k] = (_Float16)W2[i]; }
    for (int i = tid; i < 1536; i += 256) { const int o = i >> 5, k = i & 31;
        w3t[o * 36 + k] = (o < 33) ? (_Float16)W3[k * 33 + o] : (_Float16)0.f; }
    for (int i = tid; i < 3328; i += 256) {
        const int hd = i / 1664, rem = i - hd * 1664;
        const int hh = rem / 52, o = rem % 52;
        et[i] = (o >= 1 && o <= 32) ? (_Float16)eW0[hd * 1024 + (o - 1) * 32 + hh]
                                    : (_Float16)0.f;
    }
    for (int i = tid; i < 32; i += 256) { b0s[i] = b0[i]; b1s[i] = b1[i]; b2s[i] = b2[i]; }
    for (int i = tid; i < 48; i += 256) { b3s[i] = (i < 33) ? b3[i] : 0.f; }
    for (int i = tid; i < 64; i += 256) { eb0s[i] = eb0[i]; ew1s[i] = eW1[i]; }
    if (tid < 2) eb1s[tid] = eb1[tid];
    __syncthreads();

    const int wv = tid >> 6, l = tid & 63, g = l >> 4, lm = l & 15;
    const size_t ptbase = (size_t)blockIdx.x * 256 + (size_t)wv * 64;

    // ---- enc B-frags: bx[tile][kc], direct u32 pairs from ws ----
    v4h bx[4][3];
    #pragma unroll
    for (int tt = 0; tt < 4; ++tt) {
        const size_t pt = ptbase + tt * 16 + lm;
        #pragma unroll
        for (int kc = 0; kc < 3; ++kc) {
            const int lv = 8 * kc + 2 * g;
            union { uint32_t u[2]; v4h h; } c;
            c.u[0] = enc[(size_t)lv * NPTS + pt];
            c.u[1] = enc[(size_t)(lv + 1) * NPTS + pt];
            bx[tt][kc] = c.h;
        }
    }

    // ---- L0: h = relu(W0^T · enc^T + b0) ----
    v4f acc[2][4];
    #pragma unroll
    for (int m = 0; m < 2; ++m) {
        const v4f bi = *(const v4f*)(b0s + 16 * m + 4 * g);
        const v4h a0f = *(const v4h*)(w0t + (16 * m + lm) * 52 + 4 * g);
        const v4h a1f = *(const v4h*)(w0t + (16 * m + lm) * 52 + 16 + 4 * g);
        const v4h a2f = *(const v4h*)(w0t + (16 * m + lm) * 52 + 32 + 4 * g);
        #pragma unroll
        for (int tt = 0; tt < 4; ++tt) {
            v4f a = bi;
            a = MFMA16(a0f, bx[tt][0], a);
            a = MFMA16(a1f, bx[tt][1], a);
            a = MFMA16(a2f, bx[tt][2], a);
            acc[m][tt] = a;
        }
    }
    v4h bh[4][2];
    #pragma unroll
    for (int tt = 0; tt < 4; ++tt)
        #pragma unroll
        for (int m = 0; m < 2; ++m) {
            v4h h;
            #pragma unroll
            for (int r = 0; r < 4; ++r) h[r] = (_Float16)fmaxf(acc[m][tt][r], 0.f);
            bh[tt][m] = h;
        }

    // ---- L1 ----
    #pragma unroll
    for (int m = 0; m < 2; ++m) {
        const v4f bi = *(const v4f*)(b1s + 16 * m + 4 * g);
        const v4h a0f = *(const v4h*)(w1t + (16 * m + lm) * 36 + 4 * g);
        const v4h a1f = *(const v4h*)(w1t + (16 * m + lm) * 36 + 16 + 4 * g);
        #pragma unroll
        for (int tt = 0; tt < 4; ++tt) {
            v4f a = bi;
            a = MFMA16(a0f, bh[tt][0], a);
            a = MFMA16(a1f, bh[tt][1], a);
            acc[m][tt] = a;
        }
    }
    #pragma unroll
    for (int tt = 0; tt < 4; ++tt)
        #pragma unroll
        for (int m = 0; m < 2; ++m) {
            v4h h;
            #pragma unroll
            for (int r = 0; r < 4; ++r) h[r] = (_Float16)fmaxf(acc[m][tt][r], 0.f);
            bh[tt][m] = h;
        }

    // ---- L2 ----
    #pragma unroll
    for (int m = 0; m < 2; ++m) {
        const v4f bi = *(const v4f*)(b2s + 16 * m + 4 * g);
        const v4h a0f = *(const v4h*)(w2t + (16 * m + lm) * 36 + 4 * g);
        const v4h a1f = *(const v4h*)(w2t + (16 * m + lm) * 36 + 16 + 4 * g);
        #pragma unroll
        for (int tt = 0; tt < 4; ++tt) {
            v4f a = bi;
            a = MFMA16(a0f, bh[tt][0], a);
            a = MFMA16(a1f, bh[tt][1], a);
            acc[m][tt] = a;
        }
    }
    #pragma unroll
    for (int tt = 0; tt < 4; ++tt)
        #pragma unroll
        for (int m = 0; m < 2; ++m) {
            v4h h;
            #pragma unroll
            for (int r = 0; r < 4; ++r) h[r] = (_Float16)fmaxf(acc[m][tt][r], 0.f);
            bh[tt][m] = h;
        }

    // ---- L3: pred = W3^T·h + b3 (outs 0..32 real, 33..47 zero) ----
    v4f acc3[3][4];
    #pragma unroll
    for (int m = 0; m < 3; ++m) {
        const v4f bi = *(const v4f*)(b3s + 16 * m + 4 * g);
        const v4h a0f = *(const v4h*)(w3t + (16 * m + lm) * 36 + 4 * g);
        const v4h a1f = *(const v4h*)(w3t + (16 * m + lm) * 36 + 16 + 4 * g);
        #pragma unroll
        for (int tt = 0; tt < 4; ++tt) {
            v4f a = bi;
            a = MFMA16(a0f, bh[tt][0], a);
            a = MFMA16(a1f, bh[tt][1], a);
            acc3[m][tt] = a;
        }
    }
    v4h pf[4][3];
    #pragma unroll
    for (int tt = 0; tt < 4; ++tt)
        #pragma unroll
        for (int m = 0; m < 3; ++m) {
            v4h h;
            #pragma unroll
            for (int r = 0; r < 4; ++r) h[r] = (_Float16)acc3[m][tt][r];
            pf[tt][m] = h;
        }

    // ---- eps heads: he = relu(E^T·pred^T + eb0); eps = he·eW1 + eb1 ----
    float ep[2][4];
    #pragma unroll
    for (int k = 0; k < 2; ++k) {
        const v4f bi0 = *(const v4f*)(eb0s + k * 32 + 4 * g);
        const v4f bi1 = *(const v4f*)(eb0s + k * 32 + 16 + 4 * g);
        const v4f w10 = *(const v4f*)(ew1s + k * 32 + 4 * g);
        const v4f w11 = *(const v4f*)(ew1s + k * 32 + 16 + 4 * g);
        const _Float16* eb = et + (size_t)k * 1664;
        const v4h e00 = *(const v4h*)(eb + lm * 52 + 4 * g);
        const v4h e01 = *(const v4h*)(eb + lm * 52 + 16 + 4 * g);
        const v4h e02 = *(const v4h*)(eb + lm * 52 + 32 + 4 * g);
        const v4h e10 = *(const v4h*)(eb + (16 + lm) * 52 + 4 * g);
        const v4h e11 = *(const v4h*)(eb + (16 + lm) * 52 + 16 + 4 * g);
        const v4h e12 = *(const v4h*)(eb + (16 + lm) * 52 + 32 + 4 * g);
        #pragma unroll
        for (int tt = 0; tt < 4; ++tt) {
            v4f h0 = bi0, h1 = bi1;
            h0 = MFMA16(e00, pf[tt][0], h0);
            h0 = MFMA16(e01, pf[tt][1], h0);
            h0 = MFMA16(e02, pf[tt][2], h0);
            h1 = MFMA16(e10, pf[tt][0], h1);
            h1 = MFMA16(e11, pf[tt][1], h1);
            h1 = MFMA16(e12, pf[tt][2], h1);
            float p = fmaxf(h0[0], 0.f) * w10[0] + fmaxf(h0[1], 0.f) * w10[1]
                    + fmaxf(h0[2], 0.f) * w10[2] + fmaxf(h0[3], 0.f) * w10[3]
                    + fmaxf(h1[0], 0.f) * w11[0] + fmaxf(h1[1], 0.f) * w11[1]
                    + fmaxf(h1[2], 0.f) * w11[2] + fmaxf(h1[3], 0.f) * w11[3];
            p += __shfl_xor(p, 16);
            p += __shfl_xor(p, 32);
            ep[k][tt] = p + eb1s[k];
        }
    }

    // ---- epilogue: geom via LDS bounce (coalesced), sdfs/offsets by lanes<16 ----
    float* const gw = (float*)(sm + SGEOM) + wv * (16 * 36);
    #pragma unroll
    for (int tt = 0; tt < 4; ++tt) {
        #pragma unroll
        for (int m = 0; m < 3; ++m)
            #pragma unroll
            for (int r = 0; r < 4; ++r) {
                const int o = 16 * m + 4 * g + r;
                if (o >= 1 && o <= 32) gw[lm * 36 + o - 1] = acc3[m][tt][r];
            }
        __syncthreads();
        {
            const int pl = l >> 2, q = l & 3;
            const v4f g0 = *(const v4f*)(gw + pl * 36 + q * 8);
            const v4f g1 = *(const v4f*)(gw + pl * 36 + q * 8 + 4);
            float* og = out + (size_t)NPTS * 6 + (ptbase + tt * 16 + pl) * 32 + q * 8;
            *reinterpret_cast<v4f*>(og)     = g0;
            *reinterpret_cast<v4f*>(og + 4) = g1;
        }
        if (l < 16) {
            const size_t pid = ptbase + tt * 16 + l;
            const float sdf   = acc3[0][tt][0];
            const float inner = softplus_f(ep[1][tt]);
            const float outer = -softplus_f(ep[0][tt]);
            out[pid * 3 + 0] = sdf + inner + 1e-4f;
            out[pid * 3 + 1] = sdf;
            out[pid * 3 + 2] = sdf + outer - 1e-4f;
            float* oo = out + (size_t)NPTS * 3 + pid * 3;
            oo[0] = inner; oo[1] = 0.f; oo[2] = outer;
        }
        __syncthreads();
    }
}

extern "C" void kernel_launch(void* const* d_in, const int* in_sizes, int n_in,
                              void* d_out, int out_size, void* d_ws, size_t ws_size,
                              hipStream_t stream) {
    const float* points = (const float*)d_in[0];
    const float* table  = (const float*)d_in[1];
    const float* W0  = (const float*)d_in[2];
    const float* b0  = (const float*)d_in[3];
    const float* W1  = (const float*)d_in[4];
    const float* b1  = (const float*)d_in[5];
    const float* W2  = (const float*)d_in[6];
    const float* b2  = (const float*)d_in[7];
    const float* W3  = (const float*)d_in[8];
    const float* b3  = (const float*)d_in[9];
    const float* eW0 = (const float*)d_in[10];
    const float* eb0 = (const float*)d_in[11];
    const float* eW1 = (const float*)d_in[12];
    const float* eb1 = (const float*)d_in[13];
    float* out = (float*)d_out;

    ResParams rp;
    for (int l = 0; l < NLVL; ++l)
        rp.r[l] = (float)floor(16.0 * exp((double)l * log(2048.0 / 16.0) / 23.0));
    (void)in_sizes; (void)n_in; (void)out_size; (void)ws_size;

    uint32_t* enc = (uint32_t*)d_ws;   // 50.3 MB
    hash_gather_pass<<<dim3(NLVL * 512), dim3(256), 0, stream>>>(points, table, enc, rp);
    mlp_mfma<<<dim3(NPTS / 256), dim3(256), 0, stream>>>(
        enc, W0, b0, W1, b1, W2, b2, W3, b3, eW0, eb0, eW1, eb1, out);
}